// Round 14
// baseline (412.950 us; speedup 1.0000x reference)
//
#include <hip/hip_runtime.h>

// ---------------------------------------------------------------------------
// HAN forward on MI355X.
// S=16 sents, B=32 batch, T=64 tokens, E=H=256, 2H=512, NC=50, V=50000.
// R14: de-confounded retest — re-add 1-step xp register prefetch to
// k_gru_wordA (R7 vs R10 shows -5us once the f2bf regression is factored
// out). Everything else byte-identical to R13 (403us).
// ---------------------------------------------------------------------------

typedef float  f32x4  __attribute__((ext_vector_type(4)));
typedef int    i32x4  __attribute__((ext_vector_type(4)));
typedef __bf16 bf16x8 __attribute__((ext_vector_type(8)));

#define DEVINL static __device__ __forceinline__

DEVINL unsigned short f2bf(float f) {          // RNE float->bf16 (manual, 3 ops)
    unsigned int x = __builtin_bit_cast(unsigned int, f);
    x = x + 0x7fffu + ((x >> 16) & 1u);
    return (unsigned short)(x >> 16);
}
DEVINL float bf2f(unsigned short u) {
    unsigned int x = ((unsigned int)u) << 16;
    return __builtin_bit_cast(float, x);
}
DEVINL float bfe16(unsigned int v, int hi) {
    return bf2f((unsigned short)(hi ? (v >> 16) : (v & 0xffffu)));
}
DEVINL float sigm(float x) { return __builtin_amdgcn_rcpf(1.f + __expf(-x)); }
DEVINL float tanh_(float x) {
    x = fminf(fmaxf(x, -20.f), 20.f);
    float e = __expf(-2.f * x);
    return (1.f - e) * __builtin_amdgcn_rcpf(1.f + e);
}
DEVINL void mfma16(f32x4& acc, i32x4 a, i32x4 b) {
    acc = __builtin_amdgcn_mfma_f32_16x16x32_bf16(
        __builtin_bit_cast(bf16x8, a), __builtin_bit_cast(bf16x8, b), acc, 0, 0, 0);
}
DEVINL f32x4 zero4() { f32x4 v = {0.f, 0.f, 0.f, 0.f}; return v; }
DEVINL i32x4 pack8f(f32x4 v0, f32x4 v1) {
    i32x4 p;
    p.x = (int)((unsigned)f2bf(v0.x) | ((unsigned)f2bf(v0.y) << 16));
    p.y = (int)((unsigned)f2bf(v0.z) | ((unsigned)f2bf(v0.w) << 16));
    p.z = (int)((unsigned)f2bf(v1.x) | ((unsigned)f2bf(v1.y) << 16));
    p.w = (int)((unsigned)f2bf(v1.z) | ((unsigned)f2bf(v1.w) << 16));
    return p;
}

// ---- workspace layout (bytes, all 256-aligned) ----------------------------
#define O_WPWF    ((size_t)0)         // word comb fwd  [1024n][512k] bf16 frag
#define O_WPWB    ((size_t)1048576)
#define O_WPSGIH  ((size_t)2097152)   // sent Wih cat   [1536n][512k]
#define O_WPSHHF  ((size_t)3670016)   // sent Whh fwd   [768n][256k]
#define O_WPSHHB  ((size_t)4063232)
#define O_WPWW    ((size_t)4456448)   // word_W^T       [512n][512k]
#define O_WPSW    ((size_t)4980736)   // sent_W^T
#define O_BIASWF  ((size_t)5505024)   // word bias comb [4][256] f32
#define O_BIASWB  ((size_t)5509120)
#define O_BIHCAT  ((size_t)5513216)   // sent bih(+bhh r,z) cat [1536] f32
#define O_WOUT    ((size_t)5519360)   // word_out bf16 A-frag, rows 32768 x 512
#define O_SCORESW ((size_t)39073792)  // word scores f32 [32768]
#define O_SSFRAG  ((size_t)39204864)  // s bf16 A-frag, rows 512 x 512
#define O_XPSENT  ((size_t)39729152)  // xp_sent f32 [dir][bh][s][3][256][16]
#define O_SOFRAG  ((size_t)42874880)  // sent_out bf16 A-frag, rows 512 x 512
#define O_SCORESS ((size_t)43399168)  // sent scores f32 [512]
#define WS_NEED_B ((size_t)43401216)
#define O_XPW     ((size_t)43401216)  // word xp bf16 [chain][t][g][jb][rs][b][4]
#define WS_NEED_A ((size_t)144064512)

// ---------------------------------------------------------------------------
// prep: weight repacks, vectorized (8 contiguous k per thread where possible).
// ---------------------------------------------------------------------------
__global__ void k_prep(const float* wihf, const float* whhf,
                       const float* wihb, const float* whhb,
                       const float* sgihf, const float* sgihb,
                       const float* sghhf, const float* sghhb,
                       const float* wordW, const float* sentW,
                       const float* bihf, const float* bhhf,
                       const float* bihb, const float* bhhb,
                       const float* sgbihf, const float* sgbihb,
                       const float* sgbhhf, const float* sgbhhb,
                       unsigned short* Wpwf, unsigned short* Wpwb,
                       unsigned short* Wpsgih,
                       unsigned short* WpshhF, unsigned short* WpshhB,
                       unsigned short* WpwW, unsigned short* WpsW,
                       float* biasWf, float* biasWb, float* bihCat)
{
    const int tid0 = blockIdx.x * blockDim.x + threadIdx.x;
    const int nth  = gridDim.x * blockDim.x;

    // A) word combined [r|z|xn|hn] x [e(256)|h(256)], both dirs. KF=16.
    for (int c = tid0; c < 2 * 65536; c += nth) {
        int d = c >> 16, chunk = c & 65535;
        int lane = chunk & 63, nk = chunk >> 6;
        int kf = nk & 15, nf = nk >> 4;
        int n = nf * 16 + (lane & 15);
        int k0 = kf * 32 + (lane >> 4) * 8;
        int g4 = n >> 8, jj = n & 255;
        i32x4 p = {0, 0, 0, 0};
        const bool zero = (k0 < 256) ? (g4 == 3) : (g4 == 2);
        if (!zero) {
            const float* src;
            if (k0 < 256) {
                src = (d ? wihb : wihf) + (g4 * 256 + jj) * 256 + k0;
            } else {
                int row = (g4 == 3) ? (512 + jj) : (g4 * 256 + jj);
                src = (d ? whhb : whhf) + row * 256 + (k0 - 256);
            }
            p = pack8f(*(const f32x4*)src, *(const f32x4*)(src + 4));
        }
        *(i32x4*)((d ? Wpwb : Wpwf) + chunk * 8) = p;
    }
    // B) sentence Wih cat [1536n][512k]. KF=16.
    for (int chunk = tid0; chunk < 98304; chunk += nth) {
        int lane = chunk & 63, nk = chunk >> 6;
        int kf = nk & 15, nf = nk >> 4;
        int n = nf * 16 + (lane & 15);
        int k0 = kf * 32 + (lane >> 4) * 8;
        const float* src = (n < 768) ? sgihf + n * 512 + k0
                                     : sgihb + (n - 768) * 512 + k0;
        *(i32x4*)(Wpsgih + chunk * 8) =
            pack8f(*(const f32x4*)src, *(const f32x4*)(src + 4));
    }
    // C) sentence Whh f/b [768n][256k]. KF=8.
    for (int c = tid0; c < 2 * 24576; c += nth) {
        int d = c >= 24576, chunk = d ? c - 24576 : c;
        int lane = chunk & 63, nk = chunk >> 6;
        int kf = nk & 7, nf = nk >> 3;
        int n = nf * 16 + (lane & 15);
        int k0 = kf * 32 + (lane >> 4) * 8;
        const float* src = (d ? sghhb : sghhf) + n * 256 + k0;
        *(i32x4*)((d ? WpshhB : WpshhF) + chunk * 8) =
            pack8f(*(const f32x4*)src, *(const f32x4*)(src + 4));
    }
    // D) word_W / sent_W transposed: B(k,n) = W[k*512+n]. KF=16 (strided k).
    for (int c = tid0; c < 2 * 32768; c += nth) {
        int d = c >> 15, chunk = c & 32767;
        int lane = chunk & 63, nk = chunk >> 6;
        int kf = nk & 15, nf = nk >> 4;
        int n = nf * 16 + (lane & 15);
        int k0 = kf * 32 + (lane >> 4) * 8;
        const float* W = (d ? sentW : wordW) + (size_t)k0 * 512 + n;
        unsigned short us[8];
#pragma unroll
        for (int j = 0; j < 8; ++j) us[j] = f2bf(W[j * 512]);
        i32x4 p;
        p.x = (int)((unsigned)us[0] | ((unsigned)us[1] << 16));
        p.y = (int)((unsigned)us[2] | ((unsigned)us[3] << 16));
        p.z = (int)((unsigned)us[4] | ((unsigned)us[5] << 16));
        p.w = (int)((unsigned)us[6] | ((unsigned)us[7] << 16));
        *(i32x4*)((d ? WpsW : WpwW) + chunk * 8) = p;
    }
    // E) word bias comb: [r: bih+bhh][z: bih+bhh][xn: bih][hn: bhh]
    for (int idx = tid0; idx < 2048; idx += nth) {
        int d = idx >> 10, i = idx & 1023;
        int g4 = i >> 8, j = i & 255;
        const float* bi = d ? bihb : bihf;
        const float* bh = d ? bhhb : bhhf;
        float v = (g4 == 0) ? bi[j] + bh[j]
                : (g4 == 1) ? bi[256 + j] + bh[256 + j]
                : (g4 == 2) ? bi[512 + j] : bh[512 + j];
        (d ? biasWb : biasWf)[i] = v;
    }
    // F) sentence bih cat (+bhh folded for r,z; n keeps bih only)
    for (int idx = tid0; idx < 1536; idx += nth) {
        int d = idx >= 768, j = d ? idx - 768 : idx;
        const float* bi = d ? sgbihb : sgbihf;
        const float* bh = d ? sgbhhb : sgbhhf;
        bihCat[idx] = bi[j] + ((j < 512) ? bh[j] : 0.f);
    }
}

// ---------------------------------------------------------------------------
// PATH A xp GEMM (swapped): 512 WGs = (s,dir,bh,tq of 8), 8 t per WG. FROZEN.
// ---------------------------------------------------------------------------
__global__ __launch_bounds__(512, 2)
void k_xpw(const int* xg, const float* embed,
           const unsigned short* Wpwf_u, const unsigned short* Wpwb_u,
           const float* biasWf, const float* biasWb, unsigned short* xpw)
{
    __shared__ unsigned short Ebuf[2][16][256];   // 16 KiB, swizzled
    const int tid = threadIdx.x, lane = tid & 63, w = tid >> 6;
    const int cid = blockIdx.x;
    const int tq = cid & 7, bh = (cid >> 3) & 1, dir = (cid >> 4) & 1, s = cid >> 5;
    const int t0 = tq * 8;
    const i32x4* Wp = (const i32x4*)(dir ? Wpwb_u : Wpwf_u);
    const float* biasW = dir ? biasWb : biasWf;
    const int b = lane & 15, rsub = lane >> 4;

    i32x4 A[3][2][8];
#pragma unroll
    for (int g = 0; g < 3; ++g)
#pragma unroll
        for (int q = 0; q < 2; ++q)
#pragma unroll
            for (int kk = 0; kk < 8; ++kk)
                A[g][q][kk] = Wp[((g * 16 + w * 2 + q) * 16 + kk) * 64 + lane];

    unsigned int biasp[3][2][2];
#pragma unroll
    for (int g = 0; g < 3; ++g)
#pragma unroll
        for (int q = 0; q < 2; ++q) {
            const int j0 = g * 256 + (w * 2 + q) * 16 + rsub * 4;
            biasp[g][q][0] = (unsigned)f2bf(biasW[j0]) |
                             ((unsigned)f2bf(biasW[j0 + 1]) << 16);
            biasp[g][q][1] = (unsigned)f2bf(biasW[j0 + 2]) |
                             ((unsigned)f2bf(biasW[j0 + 3]) << 16);
        }

    const int sb = tid >> 5, sc = tid & 31;      // staging: b-row, e-chunk
    const int tokrow = (s * 32 + bh * 16 + sb) * 64;
    const int sdst = sb * 512 + ((sc * 16) ^ ((sb & 7) << 4));

#define STAGE_E(BUF, T)                                                       \
    {                                                                         \
        const int tok = xg[tokrow + (T)];                                     \
        const f32x4* src = (const f32x4*)(embed + (size_t)tok * 256 + sc * 8);\
        *(i32x4*)((char*)&Ebuf[BUF][0][0] + sdst) = pack8f(src[0], src[1]);   \
    }

    STAGE_E(0, t0);
    const size_t chain = (size_t)((s * 2 + dir) * 2 + bh);
    char* const xpBase = (char*)xpw + chain * 1572864 +
                         (size_t)(rsub * 128 + b * 8);

    for (int tl = 0; tl < 8; ++tl) {
        __syncthreads();
        const int t = t0 + tl, cur = tl & 1, nxt = cur ^ 1;
        if (tl < 7) STAGE_E(nxt, t + 1);

        f32x4 acc[3][2];
#pragma unroll
        for (int g = 0; g < 3; ++g) { acc[g][0] = zero4(); acc[g][1] = zero4(); }
#pragma unroll
        for (int kk = 0; kk < 8; ++kk) {
            const int roff = b * 512 + ((kk * 64 + rsub * 16) ^ ((b & 7) << 4));
            i32x4 eb = *(const i32x4*)((const char*)&Ebuf[cur][0][0] + roff);
            mfma16(acc[0][0], A[0][0][kk], eb); mfma16(acc[0][1], A[0][1][kk], eb);
            mfma16(acc[1][0], A[1][0][kk], eb); mfma16(acc[1][1], A[1][1][kk], eb);
            mfma16(acc[2][0], A[2][0][kk], eb); mfma16(acc[2][1], A[2][1][kk], eb);
        }
        char* ob = xpBase + (size_t)t * 24576;
#pragma unroll
        for (int g = 0; g < 3; ++g)
#pragma unroll
            for (int q = 0; q < 2; ++q) {
                unsigned short us[4];
#pragma unroll
                for (int i = 0; i < 4; ++i)
                    us[i] = f2bf(acc[g][q][i] + bfe16(biasp[g][q][i >> 1], i & 1));
                uint2 pk;
                pk.x = (unsigned)us[0] | ((unsigned)us[1] << 16);
                pk.y = (unsigned)us[2] | ((unsigned)us[3] << 16);
                *(uint2*)(ob + g * 8192 + (w * 2 + q) * 512) = pk;
            }
    }
#undef STAGE_E
}

// ---------------------------------------------------------------------------
// PATH A word GRU: R11 frozen base + 1-step xp register prefetch (the only
// change; de-confounded R7-vs-R10 A/B suggests -5us).
// ---------------------------------------------------------------------------
__global__ __launch_bounds__(512, 2)
void k_gru_wordA(const float* stateW,
                 const unsigned short* Wpwf_u, const unsigned short* Wpwb_u,
                 const float* biasWf, const float* biasWb,
                 const unsigned short* xpw, unsigned short* wout)
{
    __shared__ unsigned short Hbuf[2][16][256];   // 16 KiB
    const int tid = threadIdx.x, lane = tid & 63, w = tid >> 6;   // w 0..7
    const int cid = blockIdx.x, bh = cid & 1, dir = (cid >> 1) & 1, s = cid >> 2;
    const i32x4* Wp = (const i32x4*)(dir ? Wpwb_u : Wpwf_u);
    const float* biasW = dir ? biasWb : biasWf;
    const int b = lane & 15, rsub = lane >> 4;
    const int gmap[3] = {0, 1, 3};                // r, z, hn

    i32x4 A[3][2][8];
#pragma unroll
    for (int g = 0; g < 3; ++g)
#pragma unroll
        for (int q = 0; q < 2; ++q)
#pragma unroll
            for (int kk = 0; kk < 8; ++kk)
                A[g][q][kk] =
                    Wp[((gmap[g] * 16 + w * 2 + q) * 16 + 8 + kk) * 64 + lane];

    unsigned int bhnp[2][2];
    float hreg[2][4];
#pragma unroll
    for (int q = 0; q < 2; ++q) {
        const int j0 = (w * 2 + q) * 16 + rsub * 4;
        f32x4 h0 = *(const f32x4*)(stateW + dir * 8192 + (bh * 16 + b) * 256 + j0);
        bhnp[q][0] = (unsigned)f2bf(biasW[768 + j0]) |
                     ((unsigned)f2bf(biasW[768 + j0 + 1]) << 16);
        bhnp[q][1] = (unsigned)f2bf(biasW[768 + j0 + 2]) |
                     ((unsigned)f2bf(biasW[768 + j0 + 3]) << 16);
        hreg[q][0] = h0.x; hreg[q][1] = h0.y; hreg[q][2] = h0.z; hreg[q][3] = h0.w;
        uint2 pk;
        pk.x = (unsigned)f2bf(h0.x) | ((unsigned)f2bf(h0.y) << 16);
        pk.y = (unsigned)f2bf(h0.z) | ((unsigned)f2bf(h0.w) << 16);
        const int boff = b * 512 + (((w * 2 + q) * 32 + rsub * 8) ^ ((b & 7) << 4));
        *(uint2*)((char*)&Hbuf[0][0][0] + boff) = pk;
    }
    const size_t chain = (size_t)((s * 2 + dir) * 2 + bh);
    const char* const xpBase = (const char*)xpw + chain * 1572864 +
                               (size_t)(rsub * 128 + b * 8);

    // preload xp for the first step
    uint2 xpv[3][2];
    {
        const char* xb = xpBase + (size_t)(dir ? 63 : 0) * 24576;
#pragma unroll
        for (int g = 0; g < 3; ++g)
#pragma unroll
            for (int q = 0; q < 2; ++q)
                xpv[g][q] = *(const uint2*)(xb + g * 8192 + (w * 2 + q) * 512);
    }

    for (int ti = 0; ti < 64; ++ti) {
        __syncthreads();
        const int t = dir ? 63 - ti : ti;
        const int cur = ti & 1, nxt = cur ^ 1;

        // prefetch NEXT step's xp (in flight through this step's compute)
        uint2 xpn[3][2];
        if (ti < 63) {
            const char* xb = xpBase + (size_t)(dir ? t - 1 : t + 1) * 24576;
#pragma unroll
            for (int g = 0; g < 3; ++g)
#pragma unroll
                for (int q = 0; q < 2; ++q)
                    xpn[g][q] = *(const uint2*)(xb + g * 8192 + (w * 2 + q) * 512);
        }

        f32x4 acc[3][2];
#pragma unroll
        for (int g = 0; g < 3; ++g) { acc[g][0] = zero4(); acc[g][1] = zero4(); }
#pragma unroll
        for (int kk = 0; kk < 8; ++kk) {
            const int roff = b * 512 + ((kk * 64 + rsub * 16) ^ ((b & 7) << 4));
            i32x4 hb = *(const i32x4*)((const char*)&Hbuf[cur][0][0] + roff);
            mfma16(acc[0][0], A[0][0][kk], hb); mfma16(acc[0][1], A[0][1][kk], hb);
            mfma16(acc[1][0], A[1][0][kk], hb); mfma16(acc[1][1], A[1][1][kk], hb);
            mfma16(acc[2][0], A[2][0][kk], hb); mfma16(acc[2][1], A[2][1][kk], hb);
        }
        const int r = (s * 64 + t) * 32 + bh * 16 + b;
#pragma unroll
        for (int q = 0; q < 2; ++q) {
            unsigned short us[4];
#pragma unroll
            for (int i = 0; i < 4; ++i) {
                const unsigned xr = (i < 2) ? xpv[0][q].x : xpv[0][q].y;
                const unsigned xz = (i < 2) ? xpv[1][q].x : xpv[1][q].y;
                const unsigned xn = (i < 2) ? xpv[2][q].x : xpv[2][q].y;
                float rv = sigm(bfe16(xr, i & 1) + acc[0][q][i]);
                float zv = sigm(bfe16(xz, i & 1) + acc[1][q][i]);
                float nv = tanh_(bfe16(xn, i & 1) +
                                 rv * (acc[2][q][i] + bfe16(bhnp[q][i >> 1], i & 1)));
                float h = (1.f - zv) * nv + zv * hreg[q][i];
                hreg[q][i] = h;
                us[i] = f2bf(h);
            }
            uint2 pk;
            pk.x = (unsigned)us[0] | ((unsigned)us[1] << 16);
            pk.y = (unsigned)us[2] | ((unsigned)us[3] << 16);
            const int boff = b * 512 + (((w * 2 + q) * 32 + rsub * 8) ^ ((b & 7) << 4));
            *(uint2*)((char*)&Hbuf[nxt][0][0] + boff) = pk;
            const int hcol = dir * 256 + (w * 2 + q) * 16 + rsub * 4;
            const int widx = (((r >> 4) * 16 + (hcol >> 5)) * 64 + (r & 15) +
                              ((hcol >> 3) & 3) * 16) * 8 + (hcol & 7);
            *(uint2*)(wout + widx) = pk;
        }
        if (ti < 63) {
#pragma unroll
            for (int g = 0; g < 3; ++g)
#pragma unroll
                for (int q = 0; q < 2; ++q)
                    xpv[g][q] = xpn[g][q];
        }
    }
}

// ---------------------------------------------------------------------------
// attention scores: A-frags in registers, W staged 2 nf per barrier (64KB).
// ---------------------------------------------------------------------------
__global__ __launch_bounds__(1024, 4)
void k_attn_score2(const unsigned short* Afrag_u, const unsigned short* Wp_u,
                   const float* wb, const float* wp, float* scores)
{
    __shared__ i32x4 Wl[2][2][16][64];   // 64 KiB: [buf][nf-sub][kf][lane]
    const int tid = threadIdx.x, lane = tid & 63, w = tid >> 6;
    const int rblk = blockIdx.x * 16 + w;
    const i32x4* A = (const i32x4*)Afrag_u;
    const i32x4* Wg = (const i32x4*)Wp_u;

    i32x4 a[16];
#pragma unroll
    for (int kf = 0; kf < 16; ++kf) a[kf] = A[(rblk * 16 + kf) * 64 + lane];

    i32x4* wl0 = &Wl[0][0][0][0];
    i32x4* wl1 = &Wl[1][0][0][0];
    wl0[tid] = Wg[tid]; wl0[tid + 1024] = Wg[tid + 1024];

    float partial[4] = {};
    for (int np = 0; np < 16; ++np) {          // nf pair
        __syncthreads();
        if (np < 15) {
            i32x4* dst = (np & 1) ? wl0 : wl1;
            dst[tid]        = Wg[(np + 1) * 2048 + tid];
            dst[tid + 1024] = Wg[(np + 1) * 2048 + tid + 1024];
        }
        const i32x4* cur = (np & 1) ? wl1 : wl0;
#pragma unroll
        for (int sub = 0; sub < 2; ++sub) {
            f32x4 acc0 = zero4(), acc1 = zero4();
#pragma unroll
            for (int kf = 0; kf < 16; kf += 2) {
                mfma16(acc0, a[kf],     cur[sub * 1024 + kf * 64 + lane]);
                mfma16(acc1, a[kf + 1], cur[sub * 1024 + (kf + 1) * 64 + lane]);
            }
            const int n = (np * 2 + sub) * 16 + (lane & 15);
            const float wbn = wb[n], wpn = wp[n];
#pragma unroll
            for (int i = 0; i < 4; ++i)
                partial[i] += tanh_(acc0[i] + acc1[i] + wbn) * wpn;
        }
    }
#pragma unroll
    for (int i = 0; i < 4; ++i) {
        float v = partial[i];
        v += __shfl_xor(v, 1); v += __shfl_xor(v, 2);
        v += __shfl_xor(v, 4); v += __shfl_xor(v, 8);
        if ((lane & 15) == 0)
            scores[rblk * 16 + (lane >> 4) * 4 + i] = v;
    }
}

// small-row variant (sentence scores, 512 rows): 32 WGs, 4 waves split nf.
__global__ __launch_bounds__(256)
void k_attn_score_small(const unsigned short* Afrag_u,
                        const unsigned short* Wp_u,
                        const float* wb, const float* wp, float* scores)
{
    __shared__ float part[4][16];
    const int tid = threadIdx.x, lane = tid & 63, w = tid >> 6;   // w 0..3
    const int rblk = blockIdx.x;                                  // 0..31
    const i32x4* A = (const i32x4*)Afrag_u;
    const i32x4* Wp = (const i32x4*)Wp_u;
    i32x4 a[16];
#pragma unroll
    for (int kf = 0; kf < 16; ++kf) a[kf] = A[(rblk * 16 + kf) * 64 + lane];

    float partial[4] = {};
    for (int nf = w * 8; nf < w * 8 + 8; ++nf) {
        f32x4 acc0 = zero4(), acc1 = zero4();
#pragma unroll
        for (int kf = 0; kf < 16; kf += 2) {
            mfma16(acc0, a[kf],     Wp[(nf * 16 + kf) * 64 + lane]);
            mfma16(acc1, a[kf + 1], Wp[(nf * 16 + kf + 1) * 64 + lane]);
        }
        const int n = nf * 16 + (lane & 15);
        const float wbn = wb[n], wpn = wp[n];
#pragma unroll
        for (int i = 0; i < 4; ++i)
            partial[i] += tanh_(acc0[i] + acc1[i] + wbn) * wpn;
    }
#pragma unroll
    for (int i = 0; i < 4; ++i) {
        float v = partial[i];
        v += __shfl_xor(v, 1); v += __shfl_xor(v, 2);
        v += __shfl_xor(v, 4); v += __shfl_xor(v, 8);
        if ((lane & 15) == 0)
            part[w][(lane >> 4) * 4 + i] = v;
    }
    __syncthreads();
    if (tid < 16)
        scores[rblk * 16 + tid] =
            part[0][tid] + part[1][tid] + part[2][tid] + part[3][tid];
}

// ---------------------------------------------------------------------------
// word pool (coalesced): softmax over T + weighted sum -> ssFrag.
// ---------------------------------------------------------------------------
__global__ void k_word_pool(const float* scores, const unsigned short* wout,
                            unsigned short* ssFrag)
{
    __shared__ float aL16[16][64];
    const int tid = threadIdx.x;
    const int cid = blockIdx.x;
    const int oq = cid & 3, bhi = (cid >> 2) & 1, s = cid >> 3;
    const int o = oq * 256 + tid;

    if (tid < 64) {               // wave 0: softmax for this block's 16 b's
        const int l = tid;        // l = t
#pragma unroll 1
        for (int bb = 0; bb < 16; ++bb) {
            float sc = scores[s * 2048 + l * 32 + bhi * 16 + bb];
            float m = sc;
#pragma unroll
            for (int d = 1; d < 64; d <<= 1) m = fmaxf(m, __shfl_xor(m, d));
            float e = __expf(sc - m), sum = e;
#pragma unroll
            for (int d = 1; d < 64; d <<= 1) sum += __shfl_xor(sum, d);
            aL16[bb][l] = e * __builtin_amdgcn_rcpf(sum);
        }
    }
    __syncthreads();

    const int b15 = o & 15;
    const i32x4* WO = (const i32x4*)wout;
    float acc[8] = {};
#pragma unroll 4
    for (int t = 0; t < 64; ++t) {
        float at = aL16[b15][t];
        i32x4 ch = WO[(s * 128 + t * 2 + bhi) * 1024 + o];
        acc[0] += at * bf2f((unsigned short)((unsigned)ch.x & 0xffffu));
        acc[1] += at * bf2f((unsigned short)((unsigned)ch.x >> 16));
        acc[2] += at * bf2f((unsigned short)((unsigned)ch.y & 0xffffu));
        acc[3] += at * bf2f((unsigned short)((unsigned)ch.y >> 16));
        acc[4] += at * bf2f((unsigned short)((unsigned)ch.z & 0xffffu));
        acc[5] += at * bf2f((unsigned short)((unsigned)ch.z >> 16));
        acc[6] += at * bf2f((unsigned short)((unsigned)ch.w & 0xffffu));
        acc[7] += at * bf2f((unsigned short)((unsigned)ch.w >> 16));
    }
    i32x4 pk;
    pk.x = (int)((unsigned)f2bf(acc[0]) | ((unsigned)f2bf(acc[1]) << 16));
    pk.y = (int)((unsigned)f2bf(acc[2]) | ((unsigned)f2bf(acc[3]) << 16));
    pk.z = (int)((unsigned)f2bf(acc[4]) | ((unsigned)f2bf(acc[5]) << 16));
    pk.w = (int)((unsigned)f2bf(acc[6]) | ((unsigned)f2bf(acc[7]) << 16));
    ((i32x4*)ssFrag)[(s * 2 + bhi) * 1024 + o] = pk;
}

// xp_sent: s @ sg_Wih_cat^T + bihCat -> [dir][bh][s][3][256][16] f32
__global__ void k_sgih(const unsigned short* ssFrag_u, const unsigned short* Wp_u,
                       const float* bihCat, float* xpSent)
{
    const int tid = threadIdx.x, lane = tid & 63, w = tid >> 6;
    const int rblk = blockIdx.x, ncl = blockIdx.y;
    const i32x4* A = (const i32x4*)ssFrag_u;
    const i32x4* Wp = (const i32x4*)Wp_u;
    i32x4 a[16];
#pragma unroll
    for (int kf = 0; kf < 16; ++kf) a[kf] = A[(rblk * 16 + kf) * 64 + lane];
#pragma unroll
    for (int nfl = 0; nfl < 4; ++nfl) {
        const int nfg = ncl * 16 + w * 4 + nfl;
        f32x4 acc = zero4();
#pragma unroll
        for (int kf = 0; kf < 16; ++kf)
            mfma16(acc, a[kf], Wp[(nfg * 16 + kf) * 64 + lane]);
        const int n = nfg * 16 + (lane & 15);
        const float bb = bihCat[n];
        const int dir = n >= 768, ng = n - dir * 768;
        const int g = ng >> 8, jj = ng & 255;
#pragma unroll
        for (int i = 0; i < 4; ++i) {
            int row = rblk * 16 + (lane >> 4) * 4 + i;
            int s = row >> 5, b = row & 31;
            xpSent[(((dir * 2 + (b >> 4)) * 16 + s) * 12288) +
                   (g * 256 + jj) * 16 + (b & 15)] = acc[i] + bb;
        }
    }
}

// sentence GRU, register-resident Whh: 4 WGs (dir,bh), 512 thr, 16 steps.
// xp read direct global->reg at step top (mirror of word-GRU pattern).
__global__ __launch_bounds__(512)
void k_gru_sentA(const float* stateS, const unsigned short* WpF_u,
                 const unsigned short* WpB_u, const float* bhhf, const float* bhhb,
                 const float* xpSent, unsigned short* soFrag)
{
    __shared__ unsigned short Abuf[2][16][256];   // 16 KiB
    const int tid = threadIdx.x, lane = tid & 63, w = tid >> 6;
    const int cid = blockIdx.x, bh = cid & 1, dir = cid >> 1;
    const i32x4* Wp = (const i32x4*)(dir ? WpB_u : WpF_u);
    const float* bhh = dir ? bhhb : bhhf;

    i32x4 B[3][2][8];
#pragma unroll
    for (int g = 0; g < 3; ++g)
#pragma unroll
        for (int q = 0; q < 2; ++q)
#pragma unroll
            for (int kk = 0; kk < 8; ++kk)
                B[g][q][kk] = Wp[((g * 16 + w * 2 + q) * 8 + kk) * 64 + lane];

    float bhn[2];
    float hreg[2][4];
#pragma unroll
    for (int q = 0; q < 2; ++q) {
        const int j = (w * 2 + q) * 16 + (lane & 15);
        bhn[q] = bhh[512 + j];
#pragma unroll
        for (int i = 0; i < 4; ++i) {
            const int b = 4 * (lane >> 4) + i;
            float h0 = stateS[dir * 8192 + (bh * 16 + b) * 256 + j];
            hreg[q][i] = h0;
            int byteoff = b * 512 + ((j * 2) ^ ((b & 7) << 4));
            *(unsigned short*)((char*)&Abuf[0][0][0] + byteoff) = f2bf(h0);
        }
    }
    const float* const xchain = xpSent + (size_t)((dir * 2 + bh) * 16) * 12288;

    for (int si = 0; si < 16; ++si) {
        __syncthreads();
        const int s = dir ? 15 - si : si;
        const int cur = si & 1, nxt = cur ^ 1;

        // xp loads issued at step top (in flight during MFMA phase)
        f32x4 xpv[3][2];
        {
            const float* xb = xchain + (size_t)s * 12288;
#pragma unroll
            for (int g = 0; g < 3; ++g)
#pragma unroll
                for (int q = 0; q < 2; ++q) {
                    const int j = (w * 2 + q) * 16 + (lane & 15);
                    xpv[g][q] = *(const f32x4*)(xb + (g * 256 + j) * 16 +
                                                4 * (lane >> 4));
                }
        }

        f32x4 acc[3][2];
#pragma unroll
        for (int g = 0; g < 3; ++g) { acc[g][0] = zero4(); acc[g][1] = zero4(); }
#pragma unroll
        for (int kk = 0; kk < 8; ++kk) {
            const int row = lane & 15;
            const int boff = (kk * 64 + (lane >> 4) * 16) ^ ((row & 7) << 4);
            i32x4 a = *(const i32x4*)((const char*)&Abuf[cur][row][0] + boff);
#pragma unroll
            for (int g = 0; g < 3; ++g) {
                mfma16(acc[g][0], a, B[g][0][kk]);
                mfma16(acc[g][1], a, B[g][1][kk]);
            }
        }
#pragma unroll
        for (int q = 0; q < 2; ++q) {
            const int j = (w * 2 + q) * 16 + (lane & 15);
#pragma unroll
            for (int i = 0; i < 4; ++i) {
                const int b = 4 * (lane >> 4) + i;
                float rv = sigm(xpv[0][q][i] + acc[0][q][i]);
                float zv = sigm(xpv[1][q][i] + acc[1][q][i]);
                float nv = tanh_(xpv[2][q][i] + rv * (acc[2][q][i] + bhn[q]));
                float hnew = (1.f - zv) * nv + zv * hreg[q][i];
                hreg[q][i] = hnew;
                unsigned short hb = f2bf(hnew);
                int byteoff = b * 512 + ((j * 2) ^ ((b & 7) << 4));
                *(unsigned short*)((char*)&Abuf[nxt][0][0] + byteoff) = hb;
                const int r2 = s * 32 + bh * 16 + b;
                const int hcol = dir * 256 + j;
                soFrag[(((r2 >> 4) * 16 + (hcol >> 5)) * 64 + (r2 & 15) +
                        ((hcol >> 3) & 3) * 16) * 8 + (hcol & 7)] = hb;
            }
        }
    }
}

// sentence softmax over S + pool + final linear (256 thr, k-split matmul)
__global__ void k_sent_pool_fin(const float* scoresS, const unsigned short* soFrag,
                                const float* finW, const float* finb, float* out)
{
    __shared__ float aL[16];
    __shared__ float pooled[512];
    __shared__ float part[4][64];
    const int l = threadIdx.x;   // 0..255
    const int b = blockIdx.x;    // 0..31

    if (l < 64) {
        float sc = (l < 16) ? scoresS[l * 32 + b] : -1e30f;
        float m = sc;
#pragma unroll
        for (int d = 1; d < 16; d <<= 1) m = fmaxf(m, __shfl_xor(m, d));
        float e = (l < 16) ? __expf(sc - m) : 0.f;
        float sum = e;
#pragma unroll
        for (int d = 1; d < 16; d <<= 1) sum += __shfl_xor(sum, d);
        if (l < 16) aL[l] = e * __builtin_amdgcn_rcpf(sum);
    }
    __syncthreads();

    if (l < 64) {
        float acc[8] = {};
        const i32x4* SO = (const i32x4*)soFrag;
        for (int si = 0; si < 16; ++si) {
            float as = aL[si];
            int r2 = si * 32 + b;
            int cidx = ((r2 >> 4) * 16 + (l >> 2)) * 64 + (r2 & 15) + (l & 3) * 16;
            i32x4 ch = SO[cidx];
            acc[0] += as * bf2f((unsigned short)((unsigned)ch.x & 0xffffu));
            acc[1] += as * bf2f((unsigned short)((unsigned)ch.x >> 16));
            acc[2] += as * bf2f((unsigned short)((unsigned)ch.y & 0xffffu));
            acc[3] += as * bf2f((unsigned short)((unsigned)ch.y >> 16));
            acc[4] += as * bf2f((unsigned short)((unsigned)ch.z & 0xffffu));
            acc[5] += as * bf2f((unsigned short)((unsigned)ch.z >> 16));
            acc[6] += as * bf2f((unsigned short)((unsigned)ch.w & 0xffffu));
            acc[7] += as * bf2f((unsigned short)((unsigned)ch.w >> 16));
        }
#pragma unroll
        for (int q = 0; q < 8; ++q) pooled[l * 8 + q] = acc[q];
    }
    __syncthreads();
    {
        const int c = l & 63, kq = l >> 6;
        float v = 0.f;
        if (c < 50) {
            const float* wrow = finW + c * 512 + kq * 128;
            const float* pp = pooled + kq * 128;
            for (int k = 0; k < 128; ++k) v += pp[k] * wrow[k];
        }
        part[kq][c] = v;
    }
    __syncthreads();
    if (l < 50)
        out[b * 50 + l] = finb[l] + part[0][l] + part[1][l] + part[2][l] + part[3][l];
}

// ---------------------------------------------------------------------------
extern "C" void kernel_launch(void* const* d_in, const int* in_sizes, int n_in,
                              void* d_out, int out_size, void* d_ws, size_t ws_size,
                              hipStream_t stream)
{
    if (ws_size < WS_NEED_A) return;   // PATH A only (ws verified >= 144MB)

    const int*   x      = (const int*)d_in[0];
    const float* embed  = (const float*)d_in[1];
    const float* wgWihF = (const float*)d_in[2];
    const float* wgWhhF = (const float*)d_in[3];
    const float* wgBihF = (const float*)d_in[4];
    const float* wgBhhF = (const float*)d_in[5];
    const float* wgWihB = (const float*)d_in[6];
    const float* wgWhhB = (const float*)d_in[7];
    const float* wgBihB = (const float*)d_in[8];
    const float* wgBhhB = (const float*)d_in[9];
    const float* wordW  = (const float*)d_in[10];
    const float* wordB  = (const float*)d_in[11];
    const float* wordP  = (const float*)d_in[12];
    const float* sgWihF = (const float*)d_in[13];
    const float* sgWhhF = (const float*)d_in[14];
    const float* sgBihF = (const float*)d_in[15];
    const float* sgBhhF = (const float*)d_in[16];
    const float* sgWihB = (const float*)d_in[17];
    const float* sgWhhB = (const float*)d_in[18];
    const float* sgBihB = (const float*)d_in[19];
    const float* sgBhhB = (const float*)d_in[20];
    const float* sentWm = (const float*)d_in[21];
    const float* sentB  = (const float*)d_in[22];
    const float* sentP  = (const float*)d_in[23];
    const float* finW   = (const float*)d_in[24];
    const float* finB   = (const float*)d_in[25];
    const float* stateW = (const float*)d_in[26];
    const float* stateS = (const float*)d_in[27];

    char* ws = (char*)d_ws;
    unsigned short* Wpwf   = (unsigned short*)(ws + O_WPWF);
    unsigned short* Wpwb   = (unsigned short*)(ws + O_WPWB);
    unsigned short* Wpsgih = (unsigned short*)(ws + O_WPSGIH);
    unsigned short* WpshhF = (unsigned short*)(ws + O_WPSHHF);
    unsigned short* WpshhB = (unsigned short*)(ws + O_WPSHHB);
    unsigned short* WpwW   = (unsigned short*)(ws + O_WPWW);
    unsigned short* WpsW   = (unsigned short*)(ws + O_WPSW);
    float* biasWf  = (float*)(ws + O_BIASWF);
    float* biasWb  = (float*)(ws + O_BIASWB);
    float* bihCat  = (float*)(ws + O_BIHCAT);
    unsigned short* wout   = (unsigned short*)(ws + O_WOUT);
    float* scoresW = (float*)(ws + O_SCORESW);
    unsigned short* ssFrag = (unsigned short*)(ws + O_SSFRAG);
    float* xpSent  = (float*)(ws + O_XPSENT);
    unsigned short* soFrag = (unsigned short*)(ws + O_SOFRAG);
    float* scoresS = (float*)(ws + O_SCORESS);
    unsigned short* xpw    = (unsigned short*)(ws + O_XPW);

    k_prep<<<512, 256, 0, stream>>>(wgWihF, wgWhhF, wgWihB, wgWhhB,
                                    sgWihF, sgWihB, sgWhhF, sgWhhB,
                                    wordW, sentWm,
                                    wgBihF, wgBhhF, wgBihB, wgBhhB,
                                    sgBihF, sgBihB, sgBhhF, sgBhhB,
                                    Wpwf, Wpwb, Wpsgih, WpshhF, WpshhB,
                                    WpwW, WpsW, biasWf, biasWb, bihCat);

    k_xpw<<<512, 512, 0, stream>>>(x, embed, Wpwf, Wpwb, biasWf, biasWb, xpw);
    k_gru_wordA<<<64, 512, 0, stream>>>(stateW, Wpwf, Wpwb, biasWf, biasWb,
                                        xpw, wout);

    k_attn_score2<<<128, 1024, 0, stream>>>(wout, WpwW, wordB, wordP, scoresW);
    k_word_pool<<<128, 256, 0, stream>>>(scoresW, wout, ssFrag);

    k_sgih<<<dim3(32, 6), 256, 0, stream>>>(ssFrag, Wpsgih, bihCat, xpSent);
    k_gru_sentA<<<4, 512, 0, stream>>>(stateS, WpshhF, WpshhB, sgBhhF, sgBhhB,
                                       xpSent, soFrag);

    k_attn_score_small<<<32, 256, 0, stream>>>(soFrag, WpsW, sentB, sentP, scoresS);
    k_sent_pool_fin<<<32, 256, 0, stream>>>(scoresS, soFrag, finW, finB,
                                            (float*)d_out);
}

// Round 15
// 402.756 us; speedup vs baseline: 1.0253x; 1.0253x over previous
//
#include <hip/hip_runtime.h>

// ---------------------------------------------------------------------------
// HAN forward on MI355X.
// S=16 sents, B=32 batch, T=64 tokens, E=H=256, 2H=512, NC=50, V=50000.
// R15: restore R13 measured-best (403us). R14's prefetch retest regressed
// (+10us, tripwire fired) -> 5/5 scheduling interventions on k_gru_wordA
// have regressed; 189us form is final. All kernels FROZEN at R13 state.
// ---------------------------------------------------------------------------

typedef float  f32x4  __attribute__((ext_vector_type(4)));
typedef int    i32x4  __attribute__((ext_vector_type(4)));
typedef __bf16 bf16x8 __attribute__((ext_vector_type(8)));

#define DEVINL static __device__ __forceinline__

DEVINL unsigned short f2bf(float f) {          // RNE float->bf16 (manual, 3 ops)
    unsigned int x = __builtin_bit_cast(unsigned int, f);
    x = x + 0x7fffu + ((x >> 16) & 1u);
    return (unsigned short)(x >> 16);
}
DEVINL float bf2f(unsigned short u) {
    unsigned int x = ((unsigned int)u) << 16;
    return __builtin_bit_cast(float, x);
}
DEVINL float bfe16(unsigned int v, int hi) {
    return bf2f((unsigned short)(hi ? (v >> 16) : (v & 0xffffu)));
}
DEVINL float sigm(float x) { return __builtin_amdgcn_rcpf(1.f + __expf(-x)); }
DEVINL float tanh_(float x) {
    x = fminf(fmaxf(x, -20.f), 20.f);
    float e = __expf(-2.f * x);
    return (1.f - e) * __builtin_amdgcn_rcpf(1.f + e);
}
DEVINL void mfma16(f32x4& acc, i32x4 a, i32x4 b) {
    acc = __builtin_amdgcn_mfma_f32_16x16x32_bf16(
        __builtin_bit_cast(bf16x8, a), __builtin_bit_cast(bf16x8, b), acc, 0, 0, 0);
}
DEVINL f32x4 zero4() { f32x4 v = {0.f, 0.f, 0.f, 0.f}; return v; }
DEVINL i32x4 pack8f(f32x4 v0, f32x4 v1) {
    i32x4 p;
    p.x = (int)((unsigned)f2bf(v0.x) | ((unsigned)f2bf(v0.y) << 16));
    p.y = (int)((unsigned)f2bf(v0.z) | ((unsigned)f2bf(v0.w) << 16));
    p.z = (int)((unsigned)f2bf(v1.x) | ((unsigned)f2bf(v1.y) << 16));
    p.w = (int)((unsigned)f2bf(v1.z) | ((unsigned)f2bf(v1.w) << 16));
    return p;
}

// ---- workspace layout (bytes, all 256-aligned) ----------------------------
#define O_WPWF    ((size_t)0)         // word comb fwd  [1024n][512k] bf16 frag
#define O_WPWB    ((size_t)1048576)
#define O_WPSGIH  ((size_t)2097152)   // sent Wih cat   [1536n][512k]
#define O_WPSHHF  ((size_t)3670016)   // sent Whh fwd   [768n][256k]
#define O_WPSHHB  ((size_t)4063232)
#define O_WPWW    ((size_t)4456448)   // word_W^T       [512n][512k]
#define O_WPSW    ((size_t)4980736)   // sent_W^T
#define O_BIASWF  ((size_t)5505024)   // word bias comb [4][256] f32
#define O_BIASWB  ((size_t)5509120)
#define O_BIHCAT  ((size_t)5513216)   // sent bih(+bhh r,z) cat [1536] f32
#define O_WOUT    ((size_t)5519360)   // word_out bf16 A-frag, rows 32768 x 512
#define O_SCORESW ((size_t)39073792)  // word scores f32 [32768]
#define O_SSFRAG  ((size_t)39204864)  // s bf16 A-frag, rows 512 x 512
#define O_XPSENT  ((size_t)39729152)  // xp_sent f32 [dir][bh][s][3][256][16]
#define O_SOFRAG  ((size_t)42874880)  // sent_out bf16 A-frag, rows 512 x 512
#define O_SCORESS ((size_t)43399168)  // sent scores f32 [512]
#define WS_NEED_B ((size_t)43401216)
#define O_XPW     ((size_t)43401216)  // word xp bf16 [chain][t][g][jb][rs][b][4]
#define WS_NEED_A ((size_t)144064512)

// ---------------------------------------------------------------------------
// prep: weight repacks, vectorized (8 contiguous k per thread where possible).
// ---------------------------------------------------------------------------
__global__ void k_prep(const float* wihf, const float* whhf,
                       const float* wihb, const float* whhb,
                       const float* sgihf, const float* sgihb,
                       const float* sghhf, const float* sghhb,
                       const float* wordW, const float* sentW,
                       const float* bihf, const float* bhhf,
                       const float* bihb, const float* bhhb,
                       const float* sgbihf, const float* sgbihb,
                       const float* sgbhhf, const float* sgbhhb,
                       unsigned short* Wpwf, unsigned short* Wpwb,
                       unsigned short* Wpsgih,
                       unsigned short* WpshhF, unsigned short* WpshhB,
                       unsigned short* WpwW, unsigned short* WpsW,
                       float* biasWf, float* biasWb, float* bihCat)
{
    const int tid0 = blockIdx.x * blockDim.x + threadIdx.x;
    const int nth  = gridDim.x * blockDim.x;

    // A) word combined [r|z|xn|hn] x [e(256)|h(256)], both dirs. KF=16.
    for (int c = tid0; c < 2 * 65536; c += nth) {
        int d = c >> 16, chunk = c & 65535;
        int lane = chunk & 63, nk = chunk >> 6;
        int kf = nk & 15, nf = nk >> 4;
        int n = nf * 16 + (lane & 15);
        int k0 = kf * 32 + (lane >> 4) * 8;
        int g4 = n >> 8, jj = n & 255;
        i32x4 p = {0, 0, 0, 0};
        const bool zero = (k0 < 256) ? (g4 == 3) : (g4 == 2);
        if (!zero) {
            const float* src;
            if (k0 < 256) {
                src = (d ? wihb : wihf) + (g4 * 256 + jj) * 256 + k0;
            } else {
                int row = (g4 == 3) ? (512 + jj) : (g4 * 256 + jj);
                src = (d ? whhb : whhf) + row * 256 + (k0 - 256);
            }
            p = pack8f(*(const f32x4*)src, *(const f32x4*)(src + 4));
        }
        *(i32x4*)((d ? Wpwb : Wpwf) + chunk * 8) = p;
    }
    // B) sentence Wih cat [1536n][512k]. KF=16.
    for (int chunk = tid0; chunk < 98304; chunk += nth) {
        int lane = chunk & 63, nk = chunk >> 6;
        int kf = nk & 15, nf = nk >> 4;
        int n = nf * 16 + (lane & 15);
        int k0 = kf * 32 + (lane >> 4) * 8;
        const float* src = (n < 768) ? sgihf + n * 512 + k0
                                     : sgihb + (n - 768) * 512 + k0;
        *(i32x4*)(Wpsgih + chunk * 8) =
            pack8f(*(const f32x4*)src, *(const f32x4*)(src + 4));
    }
    // C) sentence Whh f/b [768n][256k]. KF=8.
    for (int c = tid0; c < 2 * 24576; c += nth) {
        int d = c >= 24576, chunk = d ? c - 24576 : c;
        int lane = chunk & 63, nk = chunk >> 6;
        int kf = nk & 7, nf = nk >> 3;
        int n = nf * 16 + (lane & 15);
        int k0 = kf * 32 + (lane >> 4) * 8;
        const float* src = (d ? sghhb : sghhf) + n * 256 + k0;
        *(i32x4*)((d ? WpshhB : WpshhF) + chunk * 8) =
            pack8f(*(const f32x4*)src, *(const f32x4*)(src + 4));
    }
    // D) word_W / sent_W transposed: B(k,n) = W[k*512+n]. KF=16 (strided k).
    for (int c = tid0; c < 2 * 32768; c += nth) {
        int d = c >> 15, chunk = c & 32767;
        int lane = chunk & 63, nk = chunk >> 6;
        int kf = nk & 15, nf = nk >> 4;
        int n = nf * 16 + (lane & 15);
        int k0 = kf * 32 + (lane >> 4) * 8;
        const float* W = (d ? sentW : wordW) + (size_t)k0 * 512 + n;
        unsigned short us[8];
#pragma unroll
        for (int j = 0; j < 8; ++j) us[j] = f2bf(W[j * 512]);
        i32x4 p;
        p.x = (int)((unsigned)us[0] | ((unsigned)us[1] << 16));
        p.y = (int)((unsigned)us[2] | ((unsigned)us[3] << 16));
        p.z = (int)((unsigned)us[4] | ((unsigned)us[5] << 16));
        p.w = (int)((unsigned)us[6] | ((unsigned)us[7] << 16));
        *(i32x4*)((d ? WpsW : WpwW) + chunk * 8) = p;
    }
    // E) word bias comb: [r: bih+bhh][z: bih+bhh][xn: bih][hn: bhh]
    for (int idx = tid0; idx < 2048; idx += nth) {
        int d = idx >> 10, i = idx & 1023;
        int g4 = i >> 8, j = i & 255;
        const float* bi = d ? bihb : bihf;
        const float* bh = d ? bhhb : bhhf;
        float v = (g4 == 0) ? bi[j] + bh[j]
                : (g4 == 1) ? bi[256 + j] + bh[256 + j]
                : (g4 == 2) ? bi[512 + j] : bh[512 + j];
        (d ? biasWb : biasWf)[i] = v;
    }
    // F) sentence bih cat (+bhh folded for r,z; n keeps bih only)
    for (int idx = tid0; idx < 1536; idx += nth) {
        int d = idx >= 768, j = d ? idx - 768 : idx;
        const float* bi = d ? sgbihb : sgbihf;
        const float* bh = d ? sgbhhb : sgbhhf;
        bihCat[idx] = bi[j] + ((j < 512) ? bh[j] : 0.f);
    }
}

// ---------------------------------------------------------------------------
// PATH A xp GEMM (swapped): 512 WGs = (s,dir,bh,tq of 8), 8 t per WG. FROZEN.
// ---------------------------------------------------------------------------
__global__ __launch_bounds__(512, 2)
void k_xpw(const int* xg, const float* embed,
           const unsigned short* Wpwf_u, const unsigned short* Wpwb_u,
           const float* biasWf, const float* biasWb, unsigned short* xpw)
{
    __shared__ unsigned short Ebuf[2][16][256];   // 16 KiB, swizzled
    const int tid = threadIdx.x, lane = tid & 63, w = tid >> 6;
    const int cid = blockIdx.x;
    const int tq = cid & 7, bh = (cid >> 3) & 1, dir = (cid >> 4) & 1, s = cid >> 5;
    const int t0 = tq * 8;
    const i32x4* Wp = (const i32x4*)(dir ? Wpwb_u : Wpwf_u);
    const float* biasW = dir ? biasWb : biasWf;
    const int b = lane & 15, rsub = lane >> 4;

    i32x4 A[3][2][8];
#pragma unroll
    for (int g = 0; g < 3; ++g)
#pragma unroll
        for (int q = 0; q < 2; ++q)
#pragma unroll
            for (int kk = 0; kk < 8; ++kk)
                A[g][q][kk] = Wp[((g * 16 + w * 2 + q) * 16 + kk) * 64 + lane];

    unsigned int biasp[3][2][2];
#pragma unroll
    for (int g = 0; g < 3; ++g)
#pragma unroll
        for (int q = 0; q < 2; ++q) {
            const int j0 = g * 256 + (w * 2 + q) * 16 + rsub * 4;
            biasp[g][q][0] = (unsigned)f2bf(biasW[j0]) |
                             ((unsigned)f2bf(biasW[j0 + 1]) << 16);
            biasp[g][q][1] = (unsigned)f2bf(biasW[j0 + 2]) |
                             ((unsigned)f2bf(biasW[j0 + 3]) << 16);
        }

    const int sb = tid >> 5, sc = tid & 31;      // staging: b-row, e-chunk
    const int tokrow = (s * 32 + bh * 16 + sb) * 64;
    const int sdst = sb * 512 + ((sc * 16) ^ ((sb & 7) << 4));

#define STAGE_E(BUF, T)                                                       \
    {                                                                         \
        const int tok = xg[tokrow + (T)];                                     \
        const f32x4* src = (const f32x4*)(embed + (size_t)tok * 256 + sc * 8);\
        *(i32x4*)((char*)&Ebuf[BUF][0][0] + sdst) = pack8f(src[0], src[1]);   \
    }

    STAGE_E(0, t0);
    const size_t chain = (size_t)((s * 2 + dir) * 2 + bh);
    char* const xpBase = (char*)xpw + chain * 1572864 +
                         (size_t)(rsub * 128 + b * 8);

    for (int tl = 0; tl < 8; ++tl) {
        __syncthreads();
        const int t = t0 + tl, cur = tl & 1, nxt = cur ^ 1;
        if (tl < 7) STAGE_E(nxt, t + 1);

        f32x4 acc[3][2];
#pragma unroll
        for (int g = 0; g < 3; ++g) { acc[g][0] = zero4(); acc[g][1] = zero4(); }
#pragma unroll
        for (int kk = 0; kk < 8; ++kk) {
            const int roff = b * 512 + ((kk * 64 + rsub * 16) ^ ((b & 7) << 4));
            i32x4 eb = *(const i32x4*)((const char*)&Ebuf[cur][0][0] + roff);
            mfma16(acc[0][0], A[0][0][kk], eb); mfma16(acc[0][1], A[0][1][kk], eb);
            mfma16(acc[1][0], A[1][0][kk], eb); mfma16(acc[1][1], A[1][1][kk], eb);
            mfma16(acc[2][0], A[2][0][kk], eb); mfma16(acc[2][1], A[2][1][kk], eb);
        }
        char* ob = xpBase + (size_t)t * 24576;
#pragma unroll
        for (int g = 0; g < 3; ++g)
#pragma unroll
            for (int q = 0; q < 2; ++q) {
                unsigned short us[4];
#pragma unroll
                for (int i = 0; i < 4; ++i)
                    us[i] = f2bf(acc[g][q][i] + bfe16(biasp[g][q][i >> 1], i & 1));
                uint2 pk;
                pk.x = (unsigned)us[0] | ((unsigned)us[1] << 16);
                pk.y = (unsigned)us[2] | ((unsigned)us[3] << 16);
                *(uint2*)(ob + g * 8192 + (w * 2 + q) * 512) = pk;
            }
    }
#undef STAGE_E
}

// ---------------------------------------------------------------------------
// PATH A word GRU — FROZEN at R5/R11 measured-best (190us). Do not touch.
// ---------------------------------------------------------------------------
__global__ __launch_bounds__(512, 2)
void k_gru_wordA(const float* stateW,
                 const unsigned short* Wpwf_u, const unsigned short* Wpwb_u,
                 const float* biasWf, const float* biasWb,
                 const unsigned short* xpw, unsigned short* wout)
{
    __shared__ unsigned short Hbuf[2][16][256];   // 16 KiB
    const int tid = threadIdx.x, lane = tid & 63, w = tid >> 6;   // w 0..7
    const int cid = blockIdx.x, bh = cid & 1, dir = (cid >> 1) & 1, s = cid >> 2;
    const i32x4* Wp = (const i32x4*)(dir ? Wpwb_u : Wpwf_u);
    const float* biasW = dir ? biasWb : biasWf;
    const int b = lane & 15, rsub = lane >> 4;
    const int gmap[3] = {0, 1, 3};                // r, z, hn

    i32x4 A[3][2][8];
#pragma unroll
    for (int g = 0; g < 3; ++g)
#pragma unroll
        for (int q = 0; q < 2; ++q)
#pragma unroll
            for (int kk = 0; kk < 8; ++kk)
                A[g][q][kk] =
                    Wp[((gmap[g] * 16 + w * 2 + q) * 16 + 8 + kk) * 64 + lane];

    unsigned int bhnp[2][2];
    float hreg[2][4];
#pragma unroll
    for (int q = 0; q < 2; ++q) {
        const int j0 = (w * 2 + q) * 16 + rsub * 4;
        f32x4 h0 = *(const f32x4*)(stateW + dir * 8192 + (bh * 16 + b) * 256 + j0);
        bhnp[q][0] = (unsigned)f2bf(biasW[768 + j0]) |
                     ((unsigned)f2bf(biasW[768 + j0 + 1]) << 16);
        bhnp[q][1] = (unsigned)f2bf(biasW[768 + j0 + 2]) |
                     ((unsigned)f2bf(biasW[768 + j0 + 3]) << 16);
        hreg[q][0] = h0.x; hreg[q][1] = h0.y; hreg[q][2] = h0.z; hreg[q][3] = h0.w;
        uint2 pk;
        pk.x = (unsigned)f2bf(h0.x) | ((unsigned)f2bf(h0.y) << 16);
        pk.y = (unsigned)f2bf(h0.z) | ((unsigned)f2bf(h0.w) << 16);
        const int boff = b * 512 + (((w * 2 + q) * 32 + rsub * 8) ^ ((b & 7) << 4));
        *(uint2*)((char*)&Hbuf[0][0][0] + boff) = pk;
    }
    const size_t chain = (size_t)((s * 2 + dir) * 2 + bh);
    const char* const xpBase = (const char*)xpw + chain * 1572864 +
                               (size_t)(rsub * 128 + b * 8);

    for (int ti = 0; ti < 64; ++ti) {
        __syncthreads();
        const int t = dir ? 63 - ti : ti;
        const int cur = ti & 1, nxt = cur ^ 1;

        uint2 xpv[3][2];
        const char* xb = xpBase + (size_t)t * 24576;
#pragma unroll
        for (int g = 0; g < 3; ++g)
#pragma unroll
            for (int q = 0; q < 2; ++q)
                xpv[g][q] = *(const uint2*)(xb + g * 8192 + (w * 2 + q) * 512);

        f32x4 acc[3][2];
#pragma unroll
        for (int g = 0; g < 3; ++g) { acc[g][0] = zero4(); acc[g][1] = zero4(); }
#pragma unroll
        for (int kk = 0; kk < 8; ++kk) {
            const int roff = b * 512 + ((kk * 64 + rsub * 16) ^ ((b & 7) << 4));
            i32x4 hb = *(const i32x4*)((const char*)&Hbuf[cur][0][0] + roff);
            mfma16(acc[0][0], A[0][0][kk], hb); mfma16(acc[0][1], A[0][1][kk], hb);
            mfma16(acc[1][0], A[1][0][kk], hb); mfma16(acc[1][1], A[1][1][kk], hb);
            mfma16(acc[2][0], A[2][0][kk], hb); mfma16(acc[2][1], A[2][1][kk], hb);
        }
        const int r = (s * 64 + t) * 32 + bh * 16 + b;
#pragma unroll
        for (int q = 0; q < 2; ++q) {
            unsigned short us[4];
#pragma unroll
            for (int i = 0; i < 4; ++i) {
                const unsigned xr = (i < 2) ? xpv[0][q].x : xpv[0][q].y;
                const unsigned xz = (i < 2) ? xpv[1][q].x : xpv[1][q].y;
                const unsigned xn = (i < 2) ? xpv[2][q].x : xpv[2][q].y;
                float rv = sigm(bfe16(xr, i & 1) + acc[0][q][i]);
                float zv = sigm(bfe16(xz, i & 1) + acc[1][q][i]);
                float nv = tanh_(bfe16(xn, i & 1) +
                                 rv * (acc[2][q][i] + bfe16(bhnp[q][i >> 1], i & 1)));
                float h = (1.f - zv) * nv + zv * hreg[q][i];
                hreg[q][i] = h;
                us[i] = f2bf(h);
            }
            uint2 pk;
            pk.x = (unsigned)us[0] | ((unsigned)us[1] << 16);
            pk.y = (unsigned)us[2] | ((unsigned)us[3] << 16);
            const int boff = b * 512 + (((w * 2 + q) * 32 + rsub * 8) ^ ((b & 7) << 4));
            *(uint2*)((char*)&Hbuf[nxt][0][0] + boff) = pk;
            const int hcol = dir * 256 + (w * 2 + q) * 16 + rsub * 4;
            const int widx = (((r >> 4) * 16 + (hcol >> 5)) * 64 + (r & 15) +
                              ((hcol >> 3) & 3) * 16) * 8 + (hcol & 7);
            *(uint2*)(wout + widx) = pk;
        }
    }
}

// ---------------------------------------------------------------------------
// attention scores: A-frags in registers, W staged 2 nf per barrier (64KB).
// ---------------------------------------------------------------------------
__global__ __launch_bounds__(1024, 4)
void k_attn_score2(const unsigned short* Afrag_u, const unsigned short* Wp_u,
                   const float* wb, const float* wp, float* scores)
{
    __shared__ i32x4 Wl[2][2][16][64];   // 64 KiB: [buf][nf-sub][kf][lane]
    const int tid = threadIdx.x, lane = tid & 63, w = tid >> 6;
    const int rblk = blockIdx.x * 16 + w;
    const i32x4* A = (const i32x4*)Afrag_u;
    const i32x4* Wg = (const i32x4*)Wp_u;

    i32x4 a[16];
#pragma unroll
    for (int kf = 0; kf < 16; ++kf) a[kf] = A[(rblk * 16 + kf) * 64 + lane];

    i32x4* wl0 = &Wl[0][0][0][0];
    i32x4* wl1 = &Wl[1][0][0][0];
    wl0[tid] = Wg[tid]; wl0[tid + 1024] = Wg[tid + 1024];

    float partial[4] = {};
    for (int np = 0; np < 16; ++np) {          // nf pair
        __syncthreads();
        if (np < 15) {
            i32x4* dst = (np & 1) ? wl0 : wl1;
            dst[tid]        = Wg[(np + 1) * 2048 + tid];
            dst[tid + 1024] = Wg[(np + 1) * 2048 + tid + 1024];
        }
        const i32x4* cur = (np & 1) ? wl1 : wl0;
#pragma unroll
        for (int sub = 0; sub < 2; ++sub) {
            f32x4 acc0 = zero4(), acc1 = zero4();
#pragma unroll
            for (int kf = 0; kf < 16; kf += 2) {
                mfma16(acc0, a[kf],     cur[sub * 1024 + kf * 64 + lane]);
                mfma16(acc1, a[kf + 1], cur[sub * 1024 + (kf + 1) * 64 + lane]);
            }
            const int n = (np * 2 + sub) * 16 + (lane & 15);
            const float wbn = wb[n], wpn = wp[n];
#pragma unroll
            for (int i = 0; i < 4; ++i)
                partial[i] += tanh_(acc0[i] + acc1[i] + wbn) * wpn;
        }
    }
#pragma unroll
    for (int i = 0; i < 4; ++i) {
        float v = partial[i];
        v += __shfl_xor(v, 1); v += __shfl_xor(v, 2);
        v += __shfl_xor(v, 4); v += __shfl_xor(v, 8);
        if ((lane & 15) == 0)
            scores[rblk * 16 + (lane >> 4) * 4 + i] = v;
    }
}

// small-row variant (sentence scores, 512 rows): 32 WGs, 4 waves split nf.
__global__ __launch_bounds__(256)
void k_attn_score_small(const unsigned short* Afrag_u,
                        const unsigned short* Wp_u,
                        const float* wb, const float* wp, float* scores)
{
    __shared__ float part[4][16];
    const int tid = threadIdx.x, lane = tid & 63, w = tid >> 6;   // w 0..3
    const int rblk = blockIdx.x;                                  // 0..31
    const i32x4* A = (const i32x4*)Afrag_u;
    const i32x4* Wp = (const i32x4*)Wp_u;
    i32x4 a[16];
#pragma unroll
    for (int kf = 0; kf < 16; ++kf) a[kf] = A[(rblk * 16 + kf) * 64 + lane];

    float partial[4] = {};
    for (int nf = w * 8; nf < w * 8 + 8; ++nf) {
        f32x4 acc0 = zero4(), acc1 = zero4();
#pragma unroll
        for (int kf = 0; kf < 16; kf += 2) {
            mfma16(acc0, a[kf],     Wp[(nf * 16 + kf) * 64 + lane]);
            mfma16(acc1, a[kf + 1], Wp[(nf * 16 + kf + 1) * 64 + lane]);
        }
        const int n = nf * 16 + (lane & 15);
        const float wbn = wb[n], wpn = wp[n];
#pragma unroll
        for (int i = 0; i < 4; ++i)
            partial[i] += tanh_(acc0[i] + acc1[i] + wbn) * wpn;
    }
#pragma unroll
    for (int i = 0; i < 4; ++i) {
        float v = partial[i];
        v += __shfl_xor(v, 1); v += __shfl_xor(v, 2);
        v += __shfl_xor(v, 4); v += __shfl_xor(v, 8);
        if ((lane & 15) == 0)
            part[w][(lane >> 4) * 4 + i] = v;
    }
    __syncthreads();
    if (tid < 16)
        scores[rblk * 16 + tid] =
            part[0][tid] + part[1][tid] + part[2][tid] + part[3][tid];
}

// ---------------------------------------------------------------------------
// word pool (coalesced): softmax over T + weighted sum -> ssFrag.
// ---------------------------------------------------------------------------
__global__ void k_word_pool(const float* scores, const unsigned short* wout,
                            unsigned short* ssFrag)
{
    __shared__ float aL16[16][64];
    const int tid = threadIdx.x;
    const int cid = blockIdx.x;
    const int oq = cid & 3, bhi = (cid >> 2) & 1, s = cid >> 3;
    const int o = oq * 256 + tid;

    if (tid < 64) {               // wave 0: softmax for this block's 16 b's
        const int l = tid;        // l = t
#pragma unroll 1
        for (int bb = 0; bb < 16; ++bb) {
            float sc = scores[s * 2048 + l * 32 + bhi * 16 + bb];
            float m = sc;
#pragma unroll
            for (int d = 1; d < 64; d <<= 1) m = fmaxf(m, __shfl_xor(m, d));
            float e = __expf(sc - m), sum = e;
#pragma unroll
            for (int d = 1; d < 64; d <<= 1) sum += __shfl_xor(sum, d);
            aL16[bb][l] = e * __builtin_amdgcn_rcpf(sum);
        }
    }
    __syncthreads();

    const int b15 = o & 15;
    const i32x4* WO = (const i32x4*)wout;
    float acc[8] = {};
#pragma unroll 4
    for (int t = 0; t < 64; ++t) {
        float at = aL16[b15][t];
        i32x4 ch = WO[(s * 128 + t * 2 + bhi) * 1024 + o];
        acc[0] += at * bf2f((unsigned short)((unsigned)ch.x & 0xffffu));
        acc[1] += at * bf2f((unsigned short)((unsigned)ch.x >> 16));
        acc[2] += at * bf2f((unsigned short)((unsigned)ch.y & 0xffffu));
        acc[3] += at * bf2f((unsigned short)((unsigned)ch.y >> 16));
        acc[4] += at * bf2f((unsigned short)((unsigned)ch.z & 0xffffu));
        acc[5] += at * bf2f((unsigned short)((unsigned)ch.z >> 16));
        acc[6] += at * bf2f((unsigned short)((unsigned)ch.w & 0xffffu));
        acc[7] += at * bf2f((unsigned short)((unsigned)ch.w >> 16));
    }
    i32x4 pk;
    pk.x = (int)((unsigned)f2bf(acc[0]) | ((unsigned)f2bf(acc[1]) << 16));
    pk.y = (int)((unsigned)f2bf(acc[2]) | ((unsigned)f2bf(acc[3]) << 16));
    pk.z = (int)((unsigned)f2bf(acc[4]) | ((unsigned)f2bf(acc[5]) << 16));
    pk.w = (int)((unsigned)f2bf(acc[6]) | ((unsigned)f2bf(acc[7]) << 16));
    ((i32x4*)ssFrag)[(s * 2 + bhi) * 1024 + o] = pk;
}

// xp_sent: s @ sg_Wih_cat^T + bihCat -> [dir][bh][s][3][256][16] f32
__global__ void k_sgih(const unsigned short* ssFrag_u, const unsigned short* Wp_u,
                       const float* bihCat, float* xpSent)
{
    const int tid = threadIdx.x, lane = tid & 63, w = tid >> 6;
    const int rblk = blockIdx.x, ncl = blockIdx.y;
    const i32x4* A = (const i32x4*)ssFrag_u;
    const i32x4* Wp = (const i32x4*)Wp_u;
    i32x4 a[16];
#pragma unroll
    for (int kf = 0; kf < 16; ++kf) a[kf] = A[(rblk * 16 + kf) * 64 + lane];
#pragma unroll
    for (int nfl = 0; nfl < 4; ++nfl) {
        const int nfg = ncl * 16 + w * 4 + nfl;
        f32x4 acc = zero4();
#pragma unroll
        for (int kf = 0; kf < 16; ++kf)
            mfma16(acc, a[kf], Wp[(nfg * 16 + kf) * 64 + lane]);
        const int n = nfg * 16 + (lane & 15);
        const float bb = bihCat[n];
        const int dir = n >= 768, ng = n - dir * 768;
        const int g = ng >> 8, jj = ng & 255;
#pragma unroll
        for (int i = 0; i < 4; ++i) {
            int row = rblk * 16 + (lane >> 4) * 4 + i;
            int s = row >> 5, b = row & 31;
            xpSent[(((dir * 2 + (b >> 4)) * 16 + s) * 12288) +
                   (g * 256 + jj) * 16 + (b & 15)] = acc[i] + bb;
        }
    }
}

// sentence GRU, register-resident Whh: 4 WGs (dir,bh), 512 thr, 16 steps.
// xp read direct global->reg at step top (mirror of word-GRU pattern).
__global__ __launch_bounds__(512)
void k_gru_sentA(const float* stateS, const unsigned short* WpF_u,
                 const unsigned short* WpB_u, const float* bhhf, const float* bhhb,
                 const float* xpSent, unsigned short* soFrag)
{
    __shared__ unsigned short Abuf[2][16][256];   // 16 KiB
    const int tid = threadIdx.x, lane = tid & 63, w = tid >> 6;
    const int cid = blockIdx.x, bh = cid & 1, dir = cid >> 1;
    const i32x4* Wp = (const i32x4*)(dir ? WpB_u : WpF_u);
    const float* bhh = dir ? bhhb : bhhf;

    i32x4 B[3][2][8];
#pragma unroll
    for (int g = 0; g < 3; ++g)
#pragma unroll
        for (int q = 0; q < 2; ++q)
#pragma unroll
            for (int kk = 0; kk < 8; ++kk)
                B[g][q][kk] = Wp[((g * 16 + w * 2 + q) * 8 + kk) * 64 + lane];

    float bhn[2];
    float hreg[2][4];
#pragma unroll
    for (int q = 0; q < 2; ++q) {
        const int j = (w * 2 + q) * 16 + (lane & 15);
        bhn[q] = bhh[512 + j];
#pragma unroll
        for (int i = 0; i < 4; ++i) {
            const int b = 4 * (lane >> 4) + i;
            float h0 = stateS[dir * 8192 + (bh * 16 + b) * 256 + j];
            hreg[q][i] = h0;
            int byteoff = b * 512 + ((j * 2) ^ ((b & 7) << 4));
            *(unsigned short*)((char*)&Abuf[0][0][0] + byteoff) = f2bf(h0);
        }
    }
    const float* const xchain = xpSent + (size_t)((dir * 2 + bh) * 16) * 12288;

    for (int si = 0; si < 16; ++si) {
        __syncthreads();
        const int s = dir ? 15 - si : si;
        const int cur = si & 1, nxt = cur ^ 1;

        // xp loads issued at step top (in flight during MFMA phase)
        f32x4 xpv[3][2];
        {
            const float* xb = xchain + (size_t)s * 12288;
#pragma unroll
            for (int g = 0; g < 3; ++g)
#pragma unroll
                for (int q = 0; q < 2; ++q) {
                    const int j = (w * 2 + q) * 16 + (lane & 15);
                    xpv[g][q] = *(const f32x4*)(xb + (g * 256 + j) * 16 +
                                                4 * (lane >> 4));
                }
        }

        f32x4 acc[3][2];
#pragma unroll
        for (int g = 0; g < 3; ++g) { acc[g][0] = zero4(); acc[g][1] = zero4(); }
#pragma unroll
        for (int kk = 0; kk < 8; ++kk) {
            const int row = lane & 15;
            const int boff = (kk * 64 + (lane >> 4) * 16) ^ ((row & 7) << 4);
            i32x4 a = *(const i32x4*)((const char*)&Abuf[cur][row][0] + boff);
#pragma unroll
            for (int g = 0; g < 3; ++g) {
                mfma16(acc[g][0], a, B[g][0][kk]);
                mfma16(acc[g][1], a, B[g][1][kk]);
            }
        }
#pragma unroll
        for (int q = 0; q < 2; ++q) {
            const int j = (w * 2 + q) * 16 + (lane & 15);
#pragma unroll
            for (int i = 0; i < 4; ++i) {
                const int b = 4 * (lane >> 4) + i;
                float rv = sigm(xpv[0][q][i] + acc[0][q][i]);
                float zv = sigm(xpv[1][q][i] + acc[1][q][i]);
                float nv = tanh_(xpv[2][q][i] + rv * (acc[2][q][i] + bhn[q]));
                float hnew = (1.f - zv) * nv + zv * hreg[q][i];
                hreg[q][i] = hnew;
                unsigned short hb = f2bf(hnew);
                int byteoff = b * 512 + ((j * 2) ^ ((b & 7) << 4));
                *(unsigned short*)((char*)&Abuf[nxt][0][0] + byteoff) = hb;
                const int r2 = s * 32 + bh * 16 + b;
                const int hcol = dir * 256 + j;
                soFrag[(((r2 >> 4) * 16 + (hcol >> 5)) * 64 + (r2 & 15) +
                        ((hcol >> 3) & 3) * 16) * 8 + (hcol & 7)] = hb;
            }
        }
    }
}

// sentence softmax over S + pool + final linear (256 thr, k-split matmul)
__global__ void k_sent_pool_fin(const float* scoresS, const unsigned short* soFrag,
                                const float* finW, const float* finb, float* out)
{
    __shared__ float aL[16];
    __shared__ float pooled[512];
    __shared__ float part[4][64];
    const int l = threadIdx.x;   // 0..255
    const int b = blockIdx.x;    // 0..31

    if (l < 64) {
        float sc = (l < 16) ? scoresS[l * 32 + b] : -1e30f;
        float m = sc;
#pragma unroll
        for (int d = 1; d < 16; d <<= 1) m = fmaxf(m, __shfl_xor(m, d));
        float e = (l < 16) ? __expf(sc - m) : 0.f;
        float sum = e;
#pragma unroll
        for (int d = 1; d < 16; d <<= 1) sum += __shfl_xor(sum, d);
        if (l < 16) aL[l] = e * __builtin_amdgcn_rcpf(sum);
    }
    __syncthreads();

    if (l < 64) {
        float acc[8] = {};
        const i32x4* SO = (const i32x4*)soFrag;
        for (int si = 0; si < 16; ++si) {
            float as = aL[si];
            int r2 = si * 32 + b;
            int cidx = ((r2 >> 4) * 16 + (l >> 2)) * 64 + (r2 & 15) + (l & 3) * 16;
            i32x4 ch = SO[cidx];
            acc[0] += as * bf2f((unsigned short)((unsigned)ch.x & 0xffffu));
            acc[1] += as * bf2f((unsigned short)((unsigned)ch.x >> 16));
            acc[2] += as * bf2f((unsigned short)((unsigned)ch.y & 0xffffu));
            acc[3] += as * bf2f((unsigned short)((unsigned)ch.y >> 16));
            acc[4] += as * bf2f((unsigned short)((unsigned)ch.z & 0xffffu));
            acc[5] += as * bf2f((unsigned short)((unsigned)ch.z >> 16));
            acc[6] += as * bf2f((unsigned short)((unsigned)ch.w & 0xffffu));
            acc[7] += as * bf2f((unsigned short)((unsigned)ch.w >> 16));
        }
#pragma unroll
        for (int q = 0; q < 8; ++q) pooled[l * 8 + q] = acc[q];
    }
    __syncthreads();
    {
        const int c = l & 63, kq = l >> 6;
        float v = 0.f;
        if (c < 50) {
            const float* wrow = finW + c * 512 + kq * 128;
            const float* pp = pooled + kq * 128;
            for (int k = 0; k < 128; ++k) v += pp[k] * wrow[k];
        }
        part[kq][c] = v;
    }
    __syncthreads();
    if (l < 50)
        out[b * 50 + l] = finb[l] + part[0][l] + part[1][l] + part[2][l] + part[3][l];
}

// ---------------------------------------------------------------------------
extern "C" void kernel_launch(void* const* d_in, const int* in_sizes, int n_in,
                              void* d_out, int out_size, void* d_ws, size_t ws_size,
                              hipStream_t stream)
{
    if (ws_size < WS_NEED_A) return;   // PATH A only (ws verified >= 144MB)

    const int*   x      = (const int*)d_in[0];
    const float* embed  = (const float*)d_in[1];
    const float* wgWihF = (const float*)d_in[2];
    const float* wgWhhF = (const float*)d_in[3];
    const float* wgBihF = (const float*)d_in[4];
    const float* wgBhhF = (const float*)d_in[5];
    const float* wgWihB = (const float*)d_in[6];
    const float* wgWhhB = (const float*)d_in[7];
    const float* wgBihB = (const float*)d_in[8];
    const float* wgBhhB = (const float*)d_in[9];
    const float* wordW  = (const float*)d_in[10];
    const float* wordB  = (const float*)d_in[11];
    const float* wordP  = (const float*)d_in[12];
    const float* sgWihF = (const float*)d_in[13];
    const float* sgWhhF = (const float*)d_in[14];
    const float* sgBihF = (const float*)d_in[15];
    const float* sgBhhF = (const float*)d_in[16];
    const float* sgWihB = (const float*)d_in[17];
    const float* sgWhhB = (const float*)d_in[18];
    const float* sgBihB = (const float*)d_in[19];
    const float* sgBhhB = (const float*)d_in[20];
    const float* sentWm = (const float*)d_in[21];
    const float* sentB  = (const float*)d_in[22];
    const float* sentP  = (const float*)d_in[23];
    const float* finW   = (const float*)d_in[24];
    const float* finB   = (const float*)d_in[25];
    const float* stateW = (const float*)d_in[26];
    const float* stateS = (const float*)d_in[27];

    char* ws = (char*)d_ws;
    unsigned short* Wpwf   = (unsigned short*)(ws + O_WPWF);
    unsigned short* Wpwb   = (unsigned short*)(ws + O_WPWB);
    unsigned short* Wpsgih = (unsigned short*)(ws + O_WPSGIH);
    unsigned short* WpshhF = (unsigned short*)(ws + O_WPSHHF);
    unsigned short* WpshhB = (unsigned short*)(ws + O_WPSHHB);
    unsigned short* WpwW   = (unsigned short*)(ws + O_WPWW);
    unsigned short* WpsW   = (unsigned short*)(ws + O_WPSW);
    float* biasWf  = (float*)(ws + O_BIASWF);
    float* biasWb  = (float*)(ws + O_BIASWB);
    float* bihCat  = (float*)(ws + O_BIHCAT);
    unsigned short* wout   = (unsigned short*)(ws + O_WOUT);
    float* scoresW = (float*)(ws + O_SCORESW);
    unsigned short* ssFrag = (unsigned short*)(ws + O_SSFRAG);
    float* xpSent  = (float*)(ws + O_XPSENT);
    unsigned short* soFrag = (unsigned short*)(ws + O_SOFRAG);
    float* scoresS = (float*)(ws + O_SCORESS);
    unsigned short* xpw    = (unsigned short*)(ws + O_XPW);

    k_prep<<<512, 256, 0, stream>>>(wgWihF, wgWhhF, wgWihB, wgWhhB,
                                    sgWihF, sgWihB, sgWhhF, sgWhhB,
                                    wordW, sentWm,
                                    wgBihF, wgBhhF, wgBihB, wgBhhB,
                                    sgBihF, sgBihB, sgBhhF, sgBhhB,
                                    Wpwf, Wpwb, Wpsgih, WpshhF, WpshhB,
                                    WpwW, WpsW, biasWf, biasWb, bihCat);

    k_xpw<<<512, 512, 0, stream>>>(x, embed, Wpwf, Wpwb, biasWf, biasWb, xpw);
    k_gru_wordA<<<64, 512, 0, stream>>>(stateW, Wpwf, Wpwb, biasWf, biasWb,
                                        xpw, wout);

    k_attn_score2<<<128, 1024, 0, stream>>>(wout, WpwW, wordB, wordP, scoresW);
    k_word_pool<<<128, 256, 0, stream>>>(scoresW, wout, ssFrag);

    k_sgih<<<dim3(32, 6), 256, 0, stream>>>(ssFrag, Wpsgih, bihCat, xpSent);
    k_gru_sentA<<<4, 512, 0, stream>>>(stateS, WpshhF, WpshhB, sgBhhF, sgBhhB,
                                       xpSent, soFrag);

    k_attn_score_small<<<32, 256, 0, stream>>>(soFrag, WpsW, sentB, sentP, scoresS);
    k_sent_pool_fin<<<32, 256, 0, stream>>>(scoresS, soFrag, finW, finB,
                                            (float*)d_out);
}